// Round 1
// baseline (36.916 us; speedup 1.0000x reference)
//
#include <hip/hip_runtime.h>
#include <math.h>

#define C_ELEC 322.0637f
#define TILE 64
#define CMAX 8

// Compute per-atom derived info (block id via searchsorted, within-block index,
// block type, partial charge, validity, path-distance-to-connections).
__device__ __forceinline__ void atom_info(
    int p, int a, int A, int B, int NBT, int APB, int C,
    const float* __restrict__ coords, const int* __restrict__ offsets,
    const int* __restrict__ block_types, const int* __restrict__ bt_n_atoms,
    const float* __restrict__ bt_pc, const int* __restrict__ bt_ipd,
    float& x, float& y, float& z, float& q,
    int& blk, int& awc, int& bt, int& valid, int* d2c)
{
    if (a >= A) {
        valid = 0; q = 0.f; x = y = z = 0.f; blk = -1; awc = 0; bt = 0;
        for (int c = 0; c < CMAX; ++c) d2c[c] = 0;
        return;
    }
    const float* cp = coords + ((size_t)p * A + a) * 3;
    x = cp[0]; y = cp[1]; z = cp[2];
    const int* off = offsets + (size_t)p * B;
    // searchsorted(off, a, side='right') - 1, clipped to [0, B-1]
    int lo = 0, hi = B;
    while (lo < hi) {
        int mid = (lo + hi) >> 1;
        if (off[mid] <= a) lo = mid + 1; else hi = mid;
    }
    blk = lo - 1;
    if (blk < 0) blk = 0;
    if (blk > B - 1) blk = B - 1;
    int aw = a - off[blk];
    bt = block_types[(size_t)p * B + blk];
    if (bt < 0) bt = 0;
    if (bt >= NBT) bt = NBT - 1;
    awc = aw < 0 ? 0 : (aw >= APB ? APB - 1 : aw);   // JAX clamps OOB indices
    q = bt_pc[(size_t)bt * APB + awc];
    valid = (aw < bt_n_atoms[bt]) ? 1 : 0;
    int Cc = C > CMAX ? CMAX : C;
    for (int c = 0; c < Cc; ++c)
        d2c[c] = bt_ipd[((size_t)bt * C + c) * APB + awc];
}

__global__ void __launch_bounds__(256)
elec_pairs_kernel(
    const float* __restrict__ coords,
    const int* __restrict__ offsets,
    const int* __restrict__ block_types,
    const int* __restrict__ inter_bondsep,   // P*B*B*C*C
    const int* __restrict__ bt_n_atoms,
    const float* __restrict__ bt_pc,
    const int* __restrict__ bt_ipd,          // NBT*C*APB
    const int* __restrict__ bt_xpd,          // NBT*APB*APB
    const float* __restrict__ gp,            // 5 floats
    float* __restrict__ partials,
    int P, int A, int B, int NBT, int APB, int C, int nt, int TP)
{
    __shared__ float s_x[TILE], s_y[TILE], s_z[TILE], s_q[TILE];
    __shared__ int s_blk[TILE], s_aw[TILE], s_bt[TILE], s_valid[TILE];
    __shared__ int s_d2c[CMAX * TILE];

    int bid = blockIdx.x;
    int p = bid / TP;
    int tp = bid - p * TP;
    // decode (ti, tj) with ti <= tj from triangular index tp
    int ti = 0, rem = tp;
    while (rem >= nt - ti) { rem -= nt - ti; ++ti; }
    int tj = ti + rem;
    int ibase = ti * TILE, jbase = tj * TILE;
    int t = threadIdx.x;

    // stage i-tile into LDS (first 64 threads)
    if (t < TILE) {
        float x, y, z, q; int blk, awc, bt, valid; int d2c[CMAX];
        atom_info(p, ibase + t, A, B, NBT, APB, C, coords, offsets, block_types,
                  bt_n_atoms, bt_pc, bt_ipd, x, y, z, q, blk, awc, bt, valid, d2c);
        s_x[t] = x; s_y[t] = y; s_z[t] = z; s_q[t] = q;
        s_blk[t] = blk; s_aw[t] = awc; s_bt[t] = bt; s_valid[t] = valid;
        for (int c = 0; c < CMAX; ++c) s_d2c[c * TILE + t] = d2c[c];
    }

    // per-thread j atom
    int jj = t & (TILE - 1);
    int jAtom = jbase + jj;
    float xj, yj, zj, qj; int blkj, awcj, btj, validj; int d2cj[CMAX];
    atom_info(p, jAtom, A, B, NBT, APB, C, coords, offsets, block_types,
              bt_n_atoms, bt_pc, bt_ipd, xj, yj, zj, qj, blkj, awcj, btj, validj, d2cj);
    __syncthreads();

    float D = gp[0], D0 = gp[1], S = gp[2], min_dis = gp[3], max_dis = gp[4];
    float xm = max_dis * S;
    float esm = D - 0.5f * (D - D0) * (2.f + 2.f * xm + xm * xm) * expf(-xm);
    float shift = 1.f / (max_dis * esm);
    int Cc = C > CMAX ? CMAX : C;

    float acc = 0.f;
    int ri = t >> 6;   // which 16-row strip of the i-tile this thread covers
    if (validj) {
        for (int ii = ri * 16; ii < ri * 16 + 16; ++ii) {
            int iAtom = ibase + ii;
            if (iAtom >= jAtom) continue;        // strict upper triangle
            if (!s_valid[ii]) continue;
            int bi = s_blk[ii];
            int bpl;
            if (bi == blkj) {
                bpl = bt_xpd[((size_t)s_bt[ii] * APB + s_aw[ii]) * APB + awcj];
            } else {
                const int* ib = inter_bondsep +
                    ((((size_t)p * B + bi) * B + blkj) * C) * C;
                int best = 0x7fffffff;
                for (int c1 = 0; c1 < Cc; ++c1) {
                    int di = s_d2c[c1 * TILE + ii];
                    for (int c2 = 0; c2 < Cc; ++c2) {
                        int v = di + ib[c1 * C + c2] + d2cj[c2];
                        if (v < best) best = v;
                    }
                }
                bpl = best;
            }
            float cpv = bpl > 4 ? 1.f : (bpl == 4 ? 0.2f : 0.f);
            if (cpv == 0.f) continue;
            float dx = s_x[ii] - xj, dy = s_y[ii] - yj, dz = s_z[ii] - zj;
            float d2 = dx * dx + dy * dy + dz * dz;
            float dist = sqrtf(fmaxf(d2, 1e-12f));
            if (dist >= max_dis) continue;
            float dc = fminf(fmaxf(dist, min_dis), max_dis);
            float xs = dc * S;
            float es = D - 0.5f * (D - D0) * (2.f + 2.f * xs + xs * xs) * expf(-xs);
            acc += C_ELEC * s_q[ii] * qj * (1.f / (dc * es) - shift) * cpv;
        }
    }

    // block reduction: wave shuffle then cross-wave via LDS
    for (int off = 32; off; off >>= 1) acc += __shfl_down(acc, off, 64);
    __shared__ float s_red[4];
    if ((t & 63) == 0) s_red[t >> 6] = acc;
    __syncthreads();
    if (t == 0) partials[bid] = s_red[0] + s_red[1] + s_red[2] + s_red[3];
}

__global__ void __launch_bounds__(256)
reduce_kernel(const float* __restrict__ partials, float* __restrict__ out,
              int TP)
{
    int p = blockIdx.x;
    float acc = 0.f;
    for (int i = threadIdx.x; i < TP; i += blockDim.x)
        acc += partials[(size_t)p * TP + i];
    for (int off = 32; off; off >>= 1) acc += __shfl_down(acc, off, 64);
    __shared__ float s[4];
    if ((threadIdx.x & 63) == 0) s[threadIdx.x >> 6] = acc;
    __syncthreads();
    if (threadIdx.x == 0) out[p] = s[0] + s[1] + s[2] + s[3];
}

extern "C" void kernel_launch(void* const* d_in, const int* in_sizes, int n_in,
                              void* d_out, int out_size, void* d_ws, size_t ws_size,
                              hipStream_t stream) {
    const float* coords        = (const float*)d_in[0];
    const int*   offsets       = (const int*)d_in[1];
    const int*   block_types   = (const int*)d_in[2];
    // d_in[3] pose_stack_min_block_bondsep: unused by reference
    const int*   inter_bondsep = (const int*)d_in[4];
    const int*   bt_n_atoms    = (const int*)d_in[5];
    const float* bt_pc         = (const float*)d_in[6];
    // d_in[7] bt_n_interblock_bonds, d_in[8] bt_atoms_forming_chemical_bonds: unused
    const int*   bt_ipd        = (const int*)d_in[9];
    const int*   bt_xpd        = (const int*)d_in[10];
    const float* gp            = (const float*)d_in[11];

    int NBT = in_sizes[5];
    int APB = in_sizes[6] / NBT;
    int PB  = in_sizes[1];
    int B   = in_sizes[3] / PB;       // (P*B*B)/(P*B)
    int P   = PB / B;
    int A   = in_sizes[0] / (3 * P);
    int C2  = in_sizes[4] / in_sizes[3];
    int C   = 1;
    while (C * C < C2) ++C;

    int nt = (A + TILE - 1) / TILE;
    int TP = nt * (nt + 1) / 2;

    float* partials = (float*)d_ws;   // P*TP floats, fully overwritten each call

    hipLaunchKernelGGL(elec_pairs_kernel, dim3(P * TP), dim3(256), 0, stream,
                       coords, offsets, block_types, inter_bondsep, bt_n_atoms,
                       bt_pc, bt_ipd, bt_xpd, gp, partials,
                       P, A, B, NBT, APB, C, nt, TP);
    hipLaunchKernelGGL(reduce_kernel, dim3(P), dim3(256), 0, stream,
                       partials, (float*)d_out, TP);
}